// Round 1
// baseline (468.630 us; speedup 1.0000x reference)
//
#include <hip/hip_runtime.h>
#include <hip/hip_bf16.h>

#define D_MODEL 4096
#define NFIB    64
#define NBATCH  4
#define LSEQ    4096
#define TM      16
#define TILES   (LSEQ / TM)

typedef __attribute__((ext_vector_type(4))) float f32x4;
typedef __attribute__((ext_vector_type(8))) short bf16x8;

__device__ __forceinline__ unsigned short f2bf(float f) {
  unsigned int u = __builtin_bit_cast(unsigned int, f);
  u += 0x7FFFu + ((u >> 16) & 1u);   // round-to-nearest-even
  return (unsigned short)(u >> 16);
}

// ---------------------------------------------------------------------------
// Q_b = (I - A_b)^{-1} (I + A_b), Gauss-Jordan in LDS, one block per batch.
// ---------------------------------------------------------------------------
__global__ void cayley_kernel(const float* __restrict__ A, float* __restrict__ Qout) {
  __shared__ float M[64][64];
  __shared__ float R[64][64];
  const int b = blockIdx.x;
  const int i = threadIdx.x;  // 0..63, one row per thread
  const float* Ab = A + b * 64 * 64;
  for (int k = 0; k < 64; ++k) {
    float a = Ab[i * 64 + k];
    float d = (i == k) ? 1.0f : 0.0f;
    M[i][k] = d - a;
    R[i][k] = d + a;
  }
  __syncthreads();
  for (int j = 0; j < 64; ++j) {
    if (i == j) {
      float inv = 1.0f / M[j][j];
      for (int k = 0; k < 64; ++k) { M[j][k] *= inv; R[j][k] *= inv; }
    }
    __syncthreads();
    if (i != j) {
      float f = M[i][j];
      for (int k = 0; k < 64; ++k) { M[i][k] -= f * M[j][k]; R[i][k] -= f * R[j][k]; }
    }
    __syncthreads();
  }
  float* Qb = Qout + b * 64 * 64;
  for (int k = 0; k < 64; ++k) Qb[i * 64 + k] = R[i][k];
}

// ---------------------------------------------------------------------------
// W_down (64 x 4096) fp32 -> bf16
// ---------------------------------------------------------------------------
__global__ void cvt_wd_kernel(const float* __restrict__ Wd, unsigned short* __restrict__ Wdb) {
  int idx = blockIdx.x * blockDim.x + threadIdx.x;
  if (idx < NFIB * D_MODEL) Wdb[idx] = f2bf(Wd[idx]);
}

// ---------------------------------------------------------------------------
// U[b][d][f] = alpha * sum_g W_up[d][g] * (Q[b][g][f] - delta(g,f)), as bf16
// ---------------------------------------------------------------------------
__global__ void prep_u_kernel(const float* __restrict__ Wup, const float* __restrict__ Q,
                              const float* __restrict__ alpha_p,
                              unsigned short* __restrict__ U) {
  int idx = blockIdx.x * blockDim.x + threadIdx.x;  // b*4096*64 + d*64 + f
  int f = idx & 63;
  int d = (idx >> 6) & (D_MODEL - 1);
  int b = idx >> 18;
  if (b >= NBATCH) return;
  const float* q = Q + b * 64 * 64;
  const float alpha = alpha_p[0];
  float s = 0.f;
#pragma unroll 8
  for (int g = 0; g < 64; ++g) {
    float qv = q[g * 64 + f] - ((g == f) ? 1.0f : 0.0f);
    s += Wup[d * 64 + g] * qv;
  }
  U[idx] = f2bf(alpha * s);
}

// ---------------------------------------------------------------------------
// Fused main kernel: one block = TM(=16) tokens of one batch, 4 waves.
// Phase 1: F = H_tile @ Wd^T  (waves split K=4096 into 4x1024, LDS reduce)
// Phase 2: Out = H_tile + F @ U_b^T (waves split N=4096 into 4x1024)
// ---------------------------------------------------------------------------
__global__ __launch_bounds__(256) void main_kernel(
    const float* __restrict__ H, const unsigned short* __restrict__ Wdb,
    const unsigned short* __restrict__ U, float* __restrict__ Out) {
  const int blk = blockIdx.x;
  const int b = blk / TILES;
  const int t = blk % TILES;
  const int row0 = b * LSEQ + t * TM;  // flat token row of tile start

  const int tid = threadIdx.x;
  const int w  = tid >> 6;   // wave 0..3
  const int l  = tid & 63;   // lane
  const int lr = l & 15;     // row/col within fragment
  const int lq = l >> 4;     // lane quarter

  __shared__ float          Fp[4][TM][NFIB + 1];  // per-wave partial F
  __shared__ unsigned short Fb[TM][NFIB + 8];     // F as bf16, padded rows

  // ---------------- Phase 1 ----------------
  f32x4 acc0 = {0,0,0,0}, acc1 = {0,0,0,0}, acc2 = {0,0,0,0}, acc3 = {0,0,0,0};
  const float* hrow = H + (size_t)(row0 + lr) * D_MODEL + w * 1024 + lq * 8;
  const unsigned short* wdbase = Wdb + w * 1024 + lq * 8;

#pragma unroll 4
  for (int s = 0; s < 32; ++s) {
    const float* hp = hrow + 32 * s;
    f32x4 h0 = *(const f32x4*)(hp);
    f32x4 h1 = *(const f32x4*)(hp + 4);
    bf16x8 a;
    a[0] = (short)f2bf(h0[0]); a[1] = (short)f2bf(h0[1]);
    a[2] = (short)f2bf(h0[2]); a[3] = (short)f2bf(h0[3]);
    a[4] = (short)f2bf(h1[0]); a[5] = (short)f2bf(h1[1]);
    a[6] = (short)f2bf(h1[2]); a[7] = (short)f2bf(h1[3]);

    const unsigned short* wp = wdbase + 32 * s;
    bf16x8 b0 = *(const bf16x8*)(wp + (0 * 16 + lr) * D_MODEL);
    bf16x8 b1 = *(const bf16x8*)(wp + (1 * 16 + lr) * D_MODEL);
    bf16x8 b2 = *(const bf16x8*)(wp + (2 * 16 + lr) * D_MODEL);
    bf16x8 b3 = *(const bf16x8*)(wp + (3 * 16 + lr) * D_MODEL);

    acc0 = __builtin_amdgcn_mfma_f32_16x16x32_bf16(a, b0, acc0, 0, 0, 0);
    acc1 = __builtin_amdgcn_mfma_f32_16x16x32_bf16(a, b1, acc1, 0, 0, 0);
    acc2 = __builtin_amdgcn_mfma_f32_16x16x32_bf16(a, b2, acc2, 0, 0, 0);
    acc3 = __builtin_amdgcn_mfma_f32_16x16x32_bf16(a, b3, acc3, 0, 0, 0);
  }

  // write per-wave partials (D layout: col=lane&15, row=4*(lane>>4)+reg)
#pragma unroll
  for (int rr = 0; rr < 4; ++rr) {
    Fp[w][lq * 4 + rr][0 * 16 + lr] = acc0[rr];
    Fp[w][lq * 4 + rr][1 * 16 + lr] = acc1[rr];
    Fp[w][lq * 4 + rr][2 * 16 + lr] = acc2[rr];
    Fp[w][lq * 4 + rr][3 * 16 + lr] = acc3[rr];
  }
  __syncthreads();

  // reduce 4 partials, convert to bf16
  for (int e = tid; e < TM * NFIB; e += 256) {
    int rrow = e >> 6, ccol = e & 63;
    float s = Fp[0][rrow][ccol] + Fp[1][rrow][ccol] +
              Fp[2][rrow][ccol] + Fp[3][rrow][ccol];
    Fb[rrow][ccol] = f2bf(s);
  }
  __syncthreads();

  // ---------------- Phase 2 ----------------
  // A-fragments of F (row=lane&15, k=8*(lane>>4)+j)
  bf16x8 fa0 = *(const bf16x8*)(&Fb[lr][lq * 8]);
  bf16x8 fa1 = *(const bf16x8*)(&Fb[lr][32 + lq * 8]);

  const unsigned short* Ub = U + (size_t)b * D_MODEL * NFIB;
  const int ncol0 = w * 1024;

#pragma unroll 2
  for (int nf = 0; nf < 64; ++nf) {
    const int n = ncol0 + nf * 16;
    const unsigned short* up = Ub + (size_t)(n + lr) * NFIB + lq * 8;
    bf16x8 ub0 = *(const bf16x8*)(up);
    bf16x8 ub1 = *(const bf16x8*)(up + 32);
    f32x4 c = {0,0,0,0};
    c = __builtin_amdgcn_mfma_f32_16x16x32_bf16(fa0, ub0, c, 0, 0, 0);
    c = __builtin_amdgcn_mfma_f32_16x16x32_bf16(fa1, ub1, c, 0, 0, 0);
#pragma unroll
    for (int rr = 0; rr < 4; ++rr) {
      size_t o = (size_t)(row0 + lq * 4 + rr) * D_MODEL + n + lr;
      Out[o] = H[o] + c[rr];
    }
  }
}

// ---------------------------------------------------------------------------
extern "C" void kernel_launch(void* const* d_in, const int* in_sizes, int n_in,
                              void* d_out, int out_size, void* d_ws, size_t ws_size,
                              hipStream_t stream) {
  const float* h_t    = (const float*)d_in[0];
  // d_in[1] = z0 (unused by the reference)
  const float* A_u    = (const float*)d_in[2];
  const float* alpha  = (const float*)d_in[3];
  const float* W_down = (const float*)d_in[4];
  const float* W_up   = (const float*)d_in[5];
  float* out = (float*)d_out;

  char* ws = (char*)d_ws;
  float*          Q   = (float*)ws;                             // 4*64*64*4   = 64 KiB
  unsigned short* Wdb = (unsigned short*)(ws + 65536);          // 64*4096*2   = 512 KiB
  unsigned short* U   = (unsigned short*)(ws + 65536 + 524288); // 4*4096*64*2 = 2 MiB

  cayley_kernel<<<NBATCH, 64, 0, stream>>>(A_u, Q);
  cvt_wd_kernel<<<(NFIB * D_MODEL) / 256, 256, 0, stream>>>(W_down, Wdb);
  prep_u_kernel<<<(NBATCH * D_MODEL * NFIB) / 256, 256, 0, stream>>>(W_up, Q, alpha, U);
  main_kernel<<<NBATCH * TILES, 256, 0, stream>>>(h_t, Wdb, U, out);
}

// Round 2
// 307.539 us; speedup vs baseline: 1.5238x; 1.5238x over previous
//
#include <hip/hip_runtime.h>
#include <hip/hip_bf16.h>

#define D_MODEL 4096
#define NFIB    64
#define NBATCH  4
#define LSEQ    4096
#define TM      16
#define TILES   (LSEQ / TM)   // 256
#define KC      512           // phase-1 K chunk
#define NKC     (D_MODEL / KC)

typedef __attribute__((ext_vector_type(4))) float f32x4;
typedef __attribute__((ext_vector_type(8))) short bf16x8;

__device__ __forceinline__ unsigned short f2bf(float f) {
  unsigned int u = __builtin_bit_cast(unsigned int, f);
  u += 0x7FFFu + ((u >> 16) & 1u);   // round-to-nearest-even
  return (unsigned short)(u >> 16);
}

// ---------------------------------------------------------------------------
// S_b = Q_b - I = 2 (I - A_b)^{-1} A_b  via Gauss-Jordan on [I-A | 2A].
// 256 threads: k = col (64), g = row-group (4x16 rows).
// ---------------------------------------------------------------------------
__global__ __launch_bounds__(256) void cayley_kernel(const float* __restrict__ A,
                                                     float* __restrict__ S) {
  __shared__ float M[64][66];
  __shared__ float R[64][66];
  const int b = blockIdx.x;
  const int tid = threadIdx.x;
  const int k = tid & 63;
  const int g = tid >> 6;
  const float* Ab = A + b * 4096;
#pragma unroll
  for (int ii = 0; ii < 16; ++ii) {
    int i = g * 16 + ii;
    float a = Ab[i * 64 + k];
    M[i][k] = ((i == k) ? 1.0f : 0.0f) - a;
    R[i][k] = 2.0f * a;
  }
  __syncthreads();
  for (int j = 0; j < 64; ++j) {
    float inv = 1.0f / M[j][j];
    __syncthreads();
    if (g == 0) { M[j][k] *= inv; R[j][k] *= inv; }
    __syncthreads();
    float mjk = M[j][k], rjk = R[j][k];
    float f[16];
#pragma unroll
    for (int ii = 0; ii < 16; ++ii) f[ii] = M[g * 16 + ii][j];
    __syncthreads();
#pragma unroll
    for (int ii = 0; ii < 16; ++ii) {
      int i = g * 16 + ii;
      if (i != j) {
        M[i][k] -= f[ii] * mjk;
        R[i][k] -= f[ii] * rjk;
      }
    }
    __syncthreads();
  }
  float* Sb = S + b * 4096;
#pragma unroll
  for (int ii = 0; ii < 16; ++ii) {
    int i = g * 16 + ii;
    Sb[i * 64 + k] = R[i][k];
  }
}

// ---------------------------------------------------------------------------
// Wd2[((ks*4+nf)*64 + lane)*8 + j] = bf16(Wd[(nf*16 + lane&15)][ks*32 + (lane>>4)*8 + j])
// -> per (ks,nf) a wave's B-fragment load is 1KB contiguous.
// ---------------------------------------------------------------------------
__global__ void cvt_wd_kernel(const float* __restrict__ Wd, unsigned short* __restrict__ Wd2) {
  int idx = blockIdx.x * 256 + threadIdx.x;   // 0..262143
  int j    = idx & 7;
  int lane = (idx >> 3) & 63;
  int nf   = (idx >> 9) & 3;
  int ks   = idx >> 11;
  int row = nf * 16 + (lane & 15);
  int col = ks * 32 + (lane >> 4) * 8 + j;
  Wd2[idx] = f2bf(Wd[row * D_MODEL + col]);
}

// ---------------------------------------------------------------------------
// U2[(((b*256+nt)*64 + lane)*2 + h)*8 + j] =
//   bf16( alpha * sum_g Wup[d][g] * S[b][g][f] ),  d = nt*16 + (lane&15),
//   f = h*32 + (lane>>4)*8 + j.  Per (b,nt) a wave reads 2KB contiguous.
// ---------------------------------------------------------------------------
__global__ void prep_u_kernel(const float* __restrict__ Wup, const float* __restrict__ S,
                              const float* __restrict__ alpha_p,
                              unsigned short* __restrict__ U2) {
  int idx = blockIdx.x * 256 + threadIdx.x;   // 0..1048575
  int j    = idx & 7;
  int h    = (idx >> 3) & 1;
  int lane = (idx >> 4) & 63;
  int nt   = (idx >> 10) & 255;
  int b    = idx >> 18;
  int d = nt * 16 + (lane & 15);
  int f = h * 32 + (lane >> 4) * 8 + j;
  const float* Sb = S + b * 4096;
  const float alpha = alpha_p[0];
  float s = 0.f;
#pragma unroll 8
  for (int g = 0; g < 64; ++g) s += Wup[d * 64 + g] * Sb[g * 64 + f];
  U2[idx] = f2bf(alpha * s);
}

// ---------------------------------------------------------------------------
// Fused main kernel. Block = 16 tokens, 256 threads (4 waves).
// Phase 1: F = H_tile @ Wd^T. H staged to LDS (bf16, XOR-swizzled) with
//          contiguous global reads; next chunk prefetched across a raw
//          s_barrier (lgkmcnt-only wait, loads stay in flight).
//          Waves split the fiber dim (wave w -> fibers w*16..w*16+15).
// Phase 2: Out = H + F @ U^T with pre-swizzled U2.
// ---------------------------------------------------------------------------
__global__ __launch_bounds__(256) void main_kernel(
    const float* __restrict__ H, const unsigned short* __restrict__ Wd2,
    const unsigned short* __restrict__ U2, float* __restrict__ Out) {
  const int blk = blockIdx.x;
  const int b = blk >> 8;
  const int t = blk & 255;
  const int row0 = b * LSEQ + t * TM;

  const int tid = threadIdx.x;
  const int w = tid >> 6, l = tid & 63, lr = l & 15, lq = l >> 4;

  __shared__ unsigned short Hs[TM * KC];                          // 16KB swizzled bf16
  __shared__ __attribute__((aligned(16))) unsigned short Fb[TM][72];

  const int srow  = w;        // this thread stages rows {srow, 4+srow, 8+srow, 12+srow}
  const int scolb = l * 16;   // byte offset within LDS row (col = l*8 bf16)

  const float* hbase = H + (size_t)row0 * D_MODEL;
  char* hsb = (char*)Hs;

  // LDS write byte addresses (fixed per thread)
  int wb[4];
#pragma unroll
  for (int j = 0; j < 4; ++j) {
    int row = 4 * j + srow;
    wb[j] = row * 1024 + (scolb ^ ((row & 7) << 4));
  }

  // prologue: load chunk 0 into registers
  f32x4 cur[8];
#pragma unroll
  for (int j = 0; j < 4; ++j) {
    const float* p = hbase + (size_t)(4 * j + srow) * D_MODEL + l * 8;
    cur[2 * j]     = *(const f32x4*)p;
    cur[2 * j + 1] = *(const f32x4*)(p + 4);
  }

  f32x4 acc = {0, 0, 0, 0};
  const unsigned short* wdbase = Wd2 + w * 512 + l * 8;

  for (int kc = 0; kc < NKC; ++kc) {
    // Hs free (prior reads done). lgkm-only wait: keep global loads in flight.
    asm volatile("s_waitcnt lgkmcnt(0)" ::: "memory");
    __builtin_amdgcn_s_barrier();

    // convert + store current chunk to LDS
#pragma unroll
    for (int j = 0; j < 4; ++j) {
      f32x4 a0 = cur[2 * j], a1 = cur[2 * j + 1];
      bf16x8 v;
      v[0] = (short)f2bf(a0[0]); v[1] = (short)f2bf(a0[1]);
      v[2] = (short)f2bf(a0[2]); v[3] = (short)f2bf(a0[3]);
      v[4] = (short)f2bf(a1[0]); v[5] = (short)f2bf(a1[1]);
      v[6] = (short)f2bf(a1[2]); v[7] = (short)f2bf(a1[3]);
      *(bf16x8*)(hsb + wb[j]) = v;
    }

    // issue next chunk's global loads (in flight across the MFMA section)
    f32x4 nxt[8];
    if (kc < NKC - 1) {
#pragma unroll
      for (int j = 0; j < 4; ++j) {
        const float* p = hbase + (size_t)(4 * j + srow) * D_MODEL + (kc + 1) * KC + l * 8;
        nxt[2 * j]     = *(const f32x4*)p;
        nxt[2 * j + 1] = *(const f32x4*)(p + 4);
      }
    }

    // Hs ready
    asm volatile("s_waitcnt lgkmcnt(0)" ::: "memory");
    __builtin_amdgcn_s_barrier();

    const unsigned short* wp = wdbase + (size_t)kc * 16 * 2048;
#pragma unroll
    for (int s = 0; s < 16; ++s) {
      bf16x8 afr = *(const bf16x8*)(hsb + lr * 1024 + ((s * 64 + lq * 16) ^ ((lr & 7) << 4)));
      bf16x8 bfr = *(const bf16x8*)(wp + (size_t)s * 2048);
      acc = __builtin_amdgcn_mfma_f32_16x16x32_bf16(afr, bfr, acc, 0, 0, 0);
    }

    if (kc < NKC - 1) {
#pragma unroll
      for (int q = 0; q < 8; ++q) cur[q] = nxt[q];
    }
  }

  // F (this wave's 16-fiber strip) -> LDS bf16
  Fb[lq * 4 + 0][w * 16 + lr] = f2bf(acc[0]);
  Fb[lq * 4 + 1][w * 16 + lr] = f2bf(acc[1]);
  Fb[lq * 4 + 2][w * 16 + lr] = f2bf(acc[2]);
  Fb[lq * 4 + 3][w * 16 + lr] = f2bf(acc[3]);
  __syncthreads();

  // ---------------- Phase 2 ----------------
  bf16x8 fa0 = *(const bf16x8*)(&Fb[lr][lq * 8]);
  bf16x8 fa1 = *(const bf16x8*)(&Fb[lr][32 + lq * 8]);

  const unsigned short* ub = U2 + (((size_t)(b * 256) + w * 64) * 64 + l) * 16;
  const int nbase = w * 1024;
#pragma unroll 4
  for (int nf = 0; nf < 64; ++nf) {
    const unsigned short* up = ub + (size_t)nf * 1024;
    bf16x8 u0 = *(const bf16x8*)(up);
    bf16x8 u1 = *(const bf16x8*)(up + 8);
    f32x4 c = {0, 0, 0, 0};
    c = __builtin_amdgcn_mfma_f32_16x16x32_bf16(fa0, u0, c, 0, 0, 0);
    c = __builtin_amdgcn_mfma_f32_16x16x32_bf16(fa1, u1, c, 0, 0, 0);
    const int n = nbase + nf * 16;
#pragma unroll
    for (int rr = 0; rr < 4; ++rr) {
      size_t o = (size_t)(row0 + lq * 4 + rr) * D_MODEL + n + lr;
      Out[o] = H[o] + c[rr];
    }
  }
}

// ---------------------------------------------------------------------------
extern "C" void kernel_launch(void* const* d_in, const int* in_sizes, int n_in,
                              void* d_out, int out_size, void* d_ws, size_t ws_size,
                              hipStream_t stream) {
  const float* h_t    = (const float*)d_in[0];
  // d_in[1] = z0 (unused by the reference)
  const float* A_u    = (const float*)d_in[2];
  const float* alpha  = (const float*)d_in[3];
  const float* W_down = (const float*)d_in[4];
  const float* W_up   = (const float*)d_in[5];
  float* out = (float*)d_out;

  char* ws = (char*)d_ws;
  float*          S   = (float*)ws;                              // 4*64*64*4   = 64 KiB
  unsigned short* Wd2 = (unsigned short*)(ws + 65536);           // 64*4096*2   = 512 KiB
  unsigned short* U2  = (unsigned short*)(ws + 65536 + 524288);  // 4*4096*64*2 = 2 MiB

  cayley_kernel<<<NBATCH, 256, 0, stream>>>(A_u, S);
  cvt_wd_kernel<<<(NFIB * D_MODEL) / 256, 256, 0, stream>>>(W_down, Wd2);
  prep_u_kernel<<<(NBATCH * D_MODEL * NFIB) / 256, 256, 0, stream>>>(W_up, S, alpha, U2);
  main_kernel<<<NBATCH * TILES, 256, 0, stream>>>(h_t, Wd2, U2, out);
}